// Round 10
// baseline (714.421 us; speedup 1.0000x reference)
//
#include <hip/hip_runtime.h>

#define NN 131072   // nodes
#define NE 262144   // edges
#define NG 4096     // graphs
#define EMBD 256

typedef unsigned short bfu;  // raw bf16 bits (storage only; compute f32)
typedef __attribute__((ext_vector_type(8))) short short8v;   // MFMA A/B frag
typedef __attribute__((ext_vector_type(4))) float f32x4;     // MFMA C/D frag

__device__ __forceinline__ float bf2f(bfu u) {
  return __uint_as_float(((unsigned)u) << 16);
}
__device__ __forceinline__ bfu f2bf(float f) {  // round-to-nearest-even
  unsigned u = __float_as_uint(f);
  u += 0x7FFF + ((u >> 16) & 1);
  return (bfu)(u >> 16);
}
__device__ __forceinline__ float4 ld4(const float* p) {
  return *reinterpret_cast<const float4*>(p);
}
__device__ __forceinline__ float4 ld4(const bfu* p) {
  ushort4 u = *reinterpret_cast<const ushort4*>(p);
  return make_float4(bf2f(u.x), bf2f(u.y), bf2f(u.z), bf2f(u.w));
}
__device__ __forceinline__ void st4(float* p, float4 v) {
  *reinterpret_cast<float4*>(p) = v;
}
__device__ __forceinline__ void st4(bfu* p, float4 v) {
  *reinterpret_cast<ushort4*>(p) =
      make_ushort4(f2bf(v.x), f2bf(v.y), f2bf(v.z), f2bf(v.w));
}
__device__ __forceinline__ void st1(float* p, float v) { *p = v; }
__device__ __forceinline__ void st1(bfu* p, float v) { *p = f2bf(v); }

// ---------------------------------------------------------------------------
__global__ __launch_bounds__(256) void k_zero(float4* p, int n4) {
  for (int i = blockIdx.x * 256 + threadIdx.x; i < n4; i += gridDim.x * 256)
    p[i] = make_float4(0.f, 0.f, 0.f, 0.f);
}

// ---------------------------------------------------------------------------
// Atom encoder: h[n][c] = sum_f atom_emb[x[n][f] + off[f]][c]. Wave = node.
__global__ __launch_bounds__(256) void k_atom_encode(
    const float* __restrict__ atom_emb, const int* __restrict__ x,
    bfu* __restrict__ h) {
  const int idx = blockIdx.x * 256 + threadIdx.x;
  const int n = idx >> 6;
  const int c = (idx & 63) << 2;
  const int off[9] = {0, 119, 123, 135, 147, 157, 163, 168, 170};
  const int* xr = x + n * 9;
  float4 acc = make_float4(0.f, 0.f, 0.f, 0.f);
#pragma unroll
  for (int f = 0; f < 9; ++f) {
    const float4 v =
        *reinterpret_cast<const float4*>(atom_emb + (xr[f] + off[f]) * EMBD + c);
    acc.x += v.x; acc.y += v.y; acc.z += v.z; acc.w += v.w;
  }
  st4(h + (size_t)n * EMBD + c, acc);
}

// ---------------------------------------------------------------------------
// CSR build over destinations + source-degree count.
__global__ __launch_bounds__(256) void k_count(const int* __restrict__ ei,
                                               float* __restrict__ deg,
                                               int* __restrict__ bcnt) {
  const int e = blockIdx.x * 256 + threadIdx.x;
  if (e >= NE) return;
  atomicAdd(&deg[ei[e]], 1.0f);
  atomicAdd(&bcnt[ei[NE + e]], 1);
}

__global__ __launch_bounds__(256) void k_bsum(const int* __restrict__ bcnt,
                                              int* __restrict__ bsum) {
  __shared__ int s[256];
  const int t = threadIdx.x;
  s[t] = bcnt[blockIdx.x * 256 + t];
  __syncthreads();
  for (int o = 128; o; o >>= 1) {
    if (t < o) s[t] += s[t + o];
    __syncthreads();
  }
  if (t == 0) bsum[blockIdx.x] = s[0];
}

__global__ __launch_bounds__(512) void k_bscan(int* __restrict__ bsum) {
  __shared__ int s[512];
  const int t = threadIdx.x;
  s[t] = bsum[t];
  __syncthreads();
  for (int o = 1; o < 512; o <<= 1) {
    const int v = (t >= o) ? s[t - o] : 0;
    __syncthreads();
    s[t] += v;
    __syncthreads();
  }
  bsum[t] = t ? s[t - 1] : 0;  // exclusive
}

__global__ __launch_bounds__(256) void k_rowptr(const int* __restrict__ bcnt,
                                                const int* __restrict__ bsum,
                                                int* __restrict__ rowptr) {
  __shared__ int s[256];
  const int t = threadIdx.x;
  const int n = blockIdx.x * 256 + t;
  s[t] = bcnt[n];
  __syncthreads();
  for (int o = 1; o < 256; o <<= 1) {
    const int v = (t >= o) ? s[t - o] : 0;
    __syncthreads();
    s[t] += v;
    __syncthreads();
  }
  rowptr[n] = bsum[blockIdx.x] + (t ? s[t - 1] : 0);
}

__global__ __launch_bounds__(256) void k_finish_deg(float* __restrict__ deg,
                                                    float* __restrict__ dinv) {
  const int n = blockIdx.x * 256 + threadIdx.x;
  const float d = deg[n] + 1.0f;
  deg[n] = d;
  dinv[n] = 1.0f / sqrtf(d);
}

// ---------------------------------------------------------------------------
// Scatter edges into CSR slots as packed records {row, combo, norm} (16 B).
// row/combo/norm are layer-invariant -> computed once here, not per layer.
__global__ __launch_bounds__(256) void k_scatter(const int* __restrict__ ei,
                                                 const int* __restrict__ ea,
                                                 const float* __restrict__ dinv,
                                                 const int* __restrict__ rowptr,
                                                 int* __restrict__ ticket,
                                                 int4* __restrict__ recs) {
  const int e = blockIdx.x * 256 + threadIdx.x;
  if (e >= NE) return;
  const int row = ei[e];
  const int col = ei[NE + e];
  const int slot = atomicAdd(&ticket[col], 1);
  const int combo = ea[e * 3] * 12 + ea[e * 3 + 1] * 2 + ea[e * 3 + 2];
  const float nm = dinv[row] * dinv[col];
  recs[rowptr[col] + slot] =
      make_int4(row, combo, __float_as_int(nm), 0);
}

// ---------------------------------------------------------------------------
// Pre-sum the 60 possible bond-embedding combinations per layer:
// combo[l][cmb][c] = bond[l][a0] + bond[l][5+a1] + bond[l][11+a2],
// cmb = a0*12 + a1*2 + a2. 3*60*256 f32 = 184 KB (L1/L2-hot in gather).
__global__ __launch_bounds__(256) void k_combo(const float* __restrict__ bond,
                                               float* __restrict__ combo) {
  const int idx = blockIdx.x * 256 + threadIdx.x;  // (l, cmb, lane)
  if (idx >= 3 * 60 * 64) return;
  const int c = (idx & 63) << 2;
  const int cmb = (idx >> 6) % 60;
  const int l = idx / (60 * 64);
  const int a0 = cmb / 12, a1 = (cmb % 12) / 2, a2 = cmb & 1;
  const float* bl = bond + l * 13 * EMBD;
  const float4 b0 = ld4(bl + a0 * EMBD + c);
  const float4 b1 = ld4(bl + (5 + a1) * EMBD + c);
  const float4 b2 = ld4(bl + (11 + a2) * EMBD + c);
  st4(combo + ((size_t)(l * 60 + cmb)) * EMBD + c,
      make_float4(b0.x + b1.x + b2.x, b0.y + b1.y + b2.y,
                  b0.z + b1.z + b2.z, b0.w + b1.w + b2.w));
}

// ---------------------------------------------------------------------------
// W split-transpose: Whi[l][n][k] = bf16(W[l][k][n]); Wlo = bf16(residual).
__global__ __launch_bounds__(256) void k_wt(const float* __restrict__ W,
                                            bfu* __restrict__ Whi,
                                            bfu* __restrict__ Wlo) {
  const int idx = blockIdx.x * 256 + threadIdx.x;  // (l,k,n), n fastest
  if (idx >= 3 * 256 * 256) return;
  const int n = idx & 255;
  const int k = (idx >> 8) & 255;
  const int l = idx >> 16;
  const float w = W[idx];
  const bfu hi = f2bf(w);
  const bfu lo = f2bf(w - bf2f(hi));
  const int o = ((l * 256 + n) << 8) + k;
  Whi[o] = hi;
  Wlo[o] = lo;
}

// ---------------------------------------------------------------------------
// bf16 MFMA GEMM, LDS-free: C[M,256] = A[M,256] @ W + bias, W = Whi+Wlo.
// Round-9 PMC: MfmaUtil 17%, VALUBusy 13%, HBM 17%, Occ 28% -> latency-bound;
// the stage+syncthreads drain and the 32KB-LDS residency cap (5 blk/CU) were
// the stall. A is L3/L2-resident (FETCH 34MB < |A|), so read fragments
// DIRECTLY from global: lanes lr,lr+16,lr+32,lr+48 cover a full 64B line.
// No LDS, no barrier; #pragma unroll 2 overlaps next-ks loads with MFMAs.
template <typename TL>
__global__ __launch_bounds__(256) void k_gemm_mfma(
    const bfu* __restrict__ A, const bfu* __restrict__ Whi,
    const bfu* __restrict__ Wlo, const float* __restrict__ bias,
    TL* __restrict__ C) {
  const int t = threadIdx.x;
  const int w = t >> 6;   // wave 0..3: cols [64w, 64w+64)
  const int l = t & 63;   // lane
  const int bm = blockIdx.x * 64;
  const int lr = l & 15;  // A-row / B-col / D-col within fragment
  const int g = l >> 4;   // k-group

  f32x4 acc[4][4];
#pragma unroll
  for (int mf = 0; mf < 4; ++mf)
#pragma unroll
    for (int nf = 0; nf < 4; ++nf) acc[mf][nf] = (f32x4)0.f;

  const bfu* arow = A + (size_t)(bm + lr) * EMBD + 8 * g;
  const bfu* bhrow = Whi + (size_t)(w * 64 + lr) * EMBD + 8 * g;
  const bfu* blrow = Wlo + (size_t)(w * 64 + lr) * EMBD + 8 * g;

#pragma unroll 2
  for (int ks = 0; ks < 8; ++ks) {
    const int k0 = ks * 32;
    short8v a[4], bh[4], bl_[4];
#pragma unroll
    for (int mf = 0; mf < 4; ++mf)
      a[mf] = *reinterpret_cast<const short8v*>(arow + mf * 16 * EMBD + k0);
#pragma unroll
    for (int nf = 0; nf < 4; ++nf) {
      bh[nf] = *reinterpret_cast<const short8v*>(bhrow + nf * 16 * EMBD + k0);
      bl_[nf] = *reinterpret_cast<const short8v*>(blrow + nf * 16 * EMBD + k0);
    }
#pragma unroll
    for (int mf = 0; mf < 4; ++mf)
#pragma unroll
      for (int nf = 0; nf < 4; ++nf) {
        acc[mf][nf] = __builtin_amdgcn_mfma_f32_16x16x32_bf16(
            a[mf], bh[nf], acc[mf][nf], 0, 0, 0);
        acc[mf][nf] = __builtin_amdgcn_mfma_f32_16x16x32_bf16(
            a[mf], bl_[nf], acc[mf][nf], 0, 0, 0);
      }
  }

  // ---- epilogue: D[row = mf*16 + g*4 + r][col = w*64 + nf*16 + lr] + bias
#pragma unroll
  for (int nf = 0; nf < 4; ++nf) {
    const int col = w * 64 + nf * 16 + lr;
    const float bv = bias[col];
#pragma unroll
    for (int mf = 0; mf < 4; ++mf) {
      const int r0 = bm + mf * 16 + g * 4;
#pragma unroll
      for (int r = 0; r < 4; ++r)
        st1(C + (size_t)(r0 + r) * EMBD + col, acc[mf][nf][r] + bv);
    }
  }
}

// ---------------------------------------------------------------------------
// Fused gather + update, wave per node. Per edge: one uniform 16B rec load,
// then two independent loads (combo table, hl gather).
template <typename TL>
__global__ __launch_bounds__(256) void k_gather_update(
    const int4* __restrict__ recs, const float* __restrict__ combo,
    const TL* __restrict__ hl, const float* __restrict__ deg,
    const int* __restrict__ bcnt, const int* __restrict__ rowptr,
    const float* __restrict__ root, const float* __restrict__ gamma,
    const float* __restrict__ beta, const float* __restrict__ mean,
    const float* __restrict__ var, bfu* __restrict__ out,
    const int do_relu) {
  const int idx = blockIdx.x * 256 + threadIdx.x;
  const int n = idx >> 6;
  const int c = (idx & 63) << 2;
  const int base = rowptr[n];
  const int cnt = bcnt[n];

  float a0 = 0.f, a1 = 0.f, a2 = 0.f, a3 = 0.f;
  for (int s = 0; s < cnt; ++s) {
    const int4 rec = recs[base + s];
    const float nm = __int_as_float(rec.z);
    const float4 ee = ld4(combo + (size_t)rec.y * EMBD + c);
    const float4 hv = ld4(hl + (size_t)rec.x * EMBD + c);
    a0 += nm * fmaxf(hv.x + ee.x, 0.f);
    a1 += nm * fmaxf(hv.y + ee.y, 0.f);
    a2 += nm * fmaxf(hv.z + ee.z, 0.f);
    a3 += nm * fmaxf(hv.w + ee.w, 0.f);
  }

  const float di = 1.0f / deg[n];
  const float4 hv = ld4(hl + (size_t)n * EMBD + c);
  const float4 r = *reinterpret_cast<const float4*>(root + c);
  const float4 mn = *reinterpret_cast<const float4*>(mean + c);
  const float4 g = *reinterpret_cast<const float4*>(gamma + c);
  const float4 vv = *reinterpret_cast<const float4*>(var + c);
  const float4 bt = *reinterpret_cast<const float4*>(beta + c);
  float v0 = a0 + fmaxf(hv.x + r.x, 0.f) * di;
  float v1 = a1 + fmaxf(hv.y + r.y, 0.f) * di;
  float v2 = a2 + fmaxf(hv.z + r.z, 0.f) * di;
  float v3 = a3 + fmaxf(hv.w + r.w, 0.f) * di;
  v0 = (v0 - mn.x) * (g.x / sqrtf(vv.x + 1e-5f)) + bt.x;
  v1 = (v1 - mn.y) * (g.y / sqrtf(vv.y + 1e-5f)) + bt.y;
  v2 = (v2 - mn.z) * (g.z / sqrtf(vv.z + 1e-5f)) + bt.z;
  v3 = (v3 - mn.w) * (g.w / sqrtf(vv.w + 1e-5f)) + bt.w;
  if (do_relu) {
    v0 = fmaxf(v0, 0.f); v1 = fmaxf(v1, 0.f);
    v2 = fmaxf(v2, 0.f); v3 = fmaxf(v3, 0.f);
  }
  st4(out + (size_t)n * EMBD + c, make_float4(v0, v1, v2, v3));
}

// ---------------------------------------------------------------------------
// Pool: batch sorted -> run-length accumulate, one atomic per (run, channel).
__global__ __launch_bounds__(256) void k_pool(const bfu* __restrict__ h,
                                              const int* __restrict__ batch,
                                              float* __restrict__ out) {
  const int c = threadIdx.x;
  const int n0 = blockIdx.x * 128;
  float acc = 0.f;
  int gprev = batch[n0];
  for (int i = 0; i < 128; ++i) {
    const int n = n0 + i;
    const int g = batch[n];
    if (g != gprev) {
      atomicAdd(&out[gprev * EMBD + c], acc);
      acc = 0.f;
      gprev = g;
    }
    acc += bf2f(h[(size_t)n * EMBD + c]);
  }
  atomicAdd(&out[gprev * EMBD + c], acc);
}

// ---------------------------------------------------------------------------
extern "C" void kernel_launch(void* const* d_in, const int* in_sizes, int n_in,
                              void* d_out, int out_size, void* d_ws,
                              size_t ws_size, hipStream_t stream) {
  const float* atom_emb = (const float*)d_in[0];
  const float* bond_emb = (const float*)d_in[1];
  const float* W = (const float*)d_in[2];
  const float* b = (const float*)d_in[3];
  const float* root = (const float*)d_in[4];
  const float* gamma = (const float*)d_in[5];
  const float* beta = (const float*)d_in[6];
  const float* mean = (const float*)d_in[7];
  const float* var = (const float*)d_in[8];
  const int* x = (const int*)d_in[9];
  const int* ei = (const int*)d_in[10];
  const int* ea = (const int*)d_in[11];
  const int* batch = (const int*)d_in[12];
  float* out = (float*)d_out;

  const size_t H = (size_t)NN * EMBD;  // elements per h buffer
  // ws layout: X (bf16, 67MB) | Y (bf16, 67MB) | recs (NE int4, 4MB) |
  //            combo (3*60*256 f32, 184KB)  => 138.6 MB total
  const size_t need = 2 * H * sizeof(bfu) + (size_t)NE * 16 +
                      (size_t)3 * 60 * EMBD * sizeof(float);
  if (ws_size < need) {  // fails validation cleanly instead of faulting
    k_zero<<<1024, 256, 0, stream>>>((float4*)out, NG * EMBD / 4);
    return;
  }
  char* ws = (char*)d_ws;
  bfu* X = (bfu*)ws;
  bfu* Y = X + H;
  int4* recs = (int4*)(ws + 2 * H * sizeof(bfu));
  float* combo = (float*)(recs + NE);

  // graph metadata + bf16 W tables live in d_out (4 MiB) until the final pool
  float* deg = out;                        // NN f32
  float* dnv = out + NN;                   // NN f32
  int* bcnt = (int*)(out + 2 * NN);        // NN
  int* rowptr = bcnt + NN;                 // NN
  int* ticket = rowptr + NN;               // NN  (dead after k_scatter)
  int* bsum = ticket + NN;                 // 512
  int* eids_spc = bsum + 512;              // NE  (spacing only)
  bfu* Whi = (bfu*)ticket;                 // 384 KB <= 512 KB, after scatter
  bfu* Wlo = (bfu*)(eids_spc + NE);        // ends at 3.89 MB <= 4 MB

  k_zero<<<1024, 256, 0, stream>>>((float4*)out, (5 * NN + 512) / 4);
  k_atom_encode<<<NN / 4, 256, 0, stream>>>(atom_emb, x, X);
  k_count<<<NE / 256, 256, 0, stream>>>(ei, deg, bcnt);
  k_bsum<<<NN / 256, 256, 0, stream>>>(bcnt, bsum);
  k_bscan<<<1, 512, 0, stream>>>(bsum);
  k_rowptr<<<NN / 256, 256, 0, stream>>>(bcnt, bsum, rowptr);
  k_finish_deg<<<NN / 256, 256, 0, stream>>>(deg, dnv);   // before scatter
  k_scatter<<<NE / 256, 256, 0, stream>>>(ei, ea, dnv, rowptr, ticket, recs);
  k_wt<<<3 * 256 * 256 / 256, 256, 0, stream>>>(W, Whi, Wlo);  // ticket dead
  k_combo<<<(3 * 60 * 64 + 255) / 256, 256, 0, stream>>>(bond_emb, combo);

  for (int l = 0; l < 3; ++l) {
    k_gemm_mfma<bfu><<<NN / 64, 256, 0, stream>>>(
        X, Whi + l * 65536, Wlo + l * 65536, b + l * EMBD, Y);
    k_gather_update<bfu><<<NN / 4, 256, 0, stream>>>(
        recs, combo + (size_t)l * 60 * EMBD, Y, deg, bcnt, rowptr,
        root + l * EMBD, gamma + l * EMBD, beta + l * EMBD, mean + l * EMBD,
        var + l * EMBD, X, (l < 2) ? 1 : 0);
  }
  // metadata now dead: zero the full output, then pool h3 (in X) into it
  k_zero<<<1024, 256, 0, stream>>>((float4*)out, NG * EMBD / 4);
  k_pool<<<NN / 128, 256, 0, stream>>>(X, batch, out);
}

// Round 11
// 582.252 us; speedup vs baseline: 1.2270x; 1.2270x over previous
//
#include <hip/hip_runtime.h>

#define NN 131072   // nodes
#define NE 262144   // edges
#define NG 4096     // graphs
#define EMBD 256

typedef unsigned short hfu;  // raw fp16 bits (storage only; compute f32)
typedef __attribute__((ext_vector_type(8))) _Float16 half8v;  // MFMA A/B frag
typedef __attribute__((ext_vector_type(4))) float f32x4;      // MFMA C/D frag

__device__ __forceinline__ float h2f(hfu u) {
  _Float16 h = *reinterpret_cast<const _Float16*>(&u);
  return (float)h;
}
__device__ __forceinline__ hfu f2h(float f) {  // RTE via v_cvt_f16_f32
  _Float16 h = (_Float16)f;
  return *reinterpret_cast<const hfu*>(&h);
}
__device__ __forceinline__ float4 ld4(const float* p) {
  return *reinterpret_cast<const float4*>(p);
}
__device__ __forceinline__ float4 ld4(const hfu* p) {
  ushort4 u = *reinterpret_cast<const ushort4*>(p);
  return make_float4(h2f(u.x), h2f(u.y), h2f(u.z), h2f(u.w));
}
__device__ __forceinline__ void st4(float* p, float4 v) {
  *reinterpret_cast<float4*>(p) = v;
}
__device__ __forceinline__ void st4(hfu* p, float4 v) {
  *reinterpret_cast<ushort4*>(p) =
      make_ushort4(f2h(v.x), f2h(v.y), f2h(v.z), f2h(v.w));
}
__device__ __forceinline__ void st1(hfu* p, float v) { *p = f2h(v); }

// ---------------------------------------------------------------------------
__global__ __launch_bounds__(256) void k_zero(float4* p, int n4) {
  for (int i = blockIdx.x * 256 + threadIdx.x; i < n4; i += gridDim.x * 256)
    p[i] = make_float4(0.f, 0.f, 0.f, 0.f);
}

// ---------------------------------------------------------------------------
// Atom encoder: h[n][c] = sum_f atom_emb[x[n][f] + off[f]][c]. Wave = node.
__global__ __launch_bounds__(256) void k_atom_encode(
    const float* __restrict__ atom_emb, const int* __restrict__ x,
    hfu* __restrict__ h) {
  const int idx = blockIdx.x * 256 + threadIdx.x;
  const int n = idx >> 6;
  const int c = (idx & 63) << 2;
  const int off[9] = {0, 119, 123, 135, 147, 157, 163, 168, 170};
  const int* xr = x + n * 9;
  float4 acc = make_float4(0.f, 0.f, 0.f, 0.f);
#pragma unroll
  for (int f = 0; f < 9; ++f) {
    const float4 v =
        *reinterpret_cast<const float4*>(atom_emb + (xr[f] + off[f]) * EMBD + c);
    acc.x += v.x; acc.y += v.y; acc.z += v.z; acc.w += v.w;
  }
  st4(h + (size_t)n * EMBD + c, acc);
}

// ---------------------------------------------------------------------------
// CSR build over destinations + source-degree count.
__global__ __launch_bounds__(256) void k_count(const int* __restrict__ ei,
                                               float* __restrict__ deg,
                                               int* __restrict__ bcnt) {
  const int e = blockIdx.x * 256 + threadIdx.x;
  if (e >= NE) return;
  atomicAdd(&deg[ei[e]], 1.0f);
  atomicAdd(&bcnt[ei[NE + e]], 1);
}

__global__ __launch_bounds__(256) void k_bsum(const int* __restrict__ bcnt,
                                              int* __restrict__ bsum) {
  __shared__ int s[256];
  const int t = threadIdx.x;
  s[t] = bcnt[blockIdx.x * 256 + t];
  __syncthreads();
  for (int o = 128; o; o >>= 1) {
    if (t < o) s[t] += s[t + o];
    __syncthreads();
  }
  if (t == 0) bsum[blockIdx.x] = s[0];
}

__global__ __launch_bounds__(512) void k_bscan(int* __restrict__ bsum) {
  __shared__ int s[512];
  const int t = threadIdx.x;
  s[t] = bsum[t];
  __syncthreads();
  for (int o = 1; o < 512; o <<= 1) {
    const int v = (t >= o) ? s[t - o] : 0;
    __syncthreads();
    s[t] += v;
    __syncthreads();
  }
  bsum[t] = t ? s[t - 1] : 0;  // exclusive
}

__global__ __launch_bounds__(256) void k_rowptr(const int* __restrict__ bcnt,
                                                const int* __restrict__ bsum,
                                                int* __restrict__ rowptr) {
  __shared__ int s[256];
  const int t = threadIdx.x;
  const int n = blockIdx.x * 256 + t;
  s[t] = bcnt[n];
  __syncthreads();
  for (int o = 1; o < 256; o <<= 1) {
    const int v = (t >= o) ? s[t - o] : 0;
    __syncthreads();
    s[t] += v;
    __syncthreads();
  }
  rowptr[n] = bsum[blockIdx.x] + (t ? s[t - 1] : 0);
}

__global__ __launch_bounds__(256) void k_finish_deg(float* __restrict__ deg,
                                                    float* __restrict__ dinv) {
  const int n = blockIdx.x * 256 + threadIdx.x;
  const float d = deg[n] + 1.0f;
  deg[n] = d;
  dinv[n] = 1.0f / sqrtf(d);
}

// ---------------------------------------------------------------------------
// Scatter edges into CSR slots as packed records {row, combo, norm} (16 B).
__global__ __launch_bounds__(256) void k_scatter(const int* __restrict__ ei,
                                                 const int* __restrict__ ea,
                                                 const float* __restrict__ dinv,
                                                 const int* __restrict__ rowptr,
                                                 int* __restrict__ ticket,
                                                 int4* __restrict__ recs) {
  const int e = blockIdx.x * 256 + threadIdx.x;
  if (e >= NE) return;
  const int row = ei[e];
  const int col = ei[NE + e];
  const int slot = atomicAdd(&ticket[col], 1);
  const int combo = ea[e * 3] * 12 + ea[e * 3 + 1] * 2 + ea[e * 3 + 2];
  const float nm = dinv[row] * dinv[col];
  recs[rowptr[col] + slot] =
      make_int4(row, combo, __float_as_int(nm), 0);
}

// ---------------------------------------------------------------------------
// Pre-sum the 60 possible bond-embedding combinations per layer (184 KB).
__global__ __launch_bounds__(256) void k_combo(const float* __restrict__ bond,
                                               float* __restrict__ combo) {
  const int idx = blockIdx.x * 256 + threadIdx.x;  // (l, cmb, lane)
  if (idx >= 3 * 60 * 64) return;
  const int c = (idx & 63) << 2;
  const int cmb = (idx >> 6) % 60;
  const int l = idx / (60 * 64);
  const int a0 = cmb / 12, a1 = (cmb % 12) / 2, a2 = cmb & 1;
  const float* bl = bond + l * 13 * EMBD;
  const float4 b0 = ld4(bl + a0 * EMBD + c);
  const float4 b1 = ld4(bl + (5 + a1) * EMBD + c);
  const float4 b2 = ld4(bl + (11 + a2) * EMBD + c);
  st4(combo + ((size_t)(l * 60 + cmb)) * EMBD + c,
      make_float4(b0.x + b1.x + b2.x, b0.y + b1.y + b2.y,
                  b0.z + b1.z + b2.z, b0.w + b1.w + b2.w));
}

// ---------------------------------------------------------------------------
// W transpose to fp16: Wt[l][n][k] = fp16(W[l][k][n]). Single table — fp16's
// 11 mantissa bits beat the old bf16 split-hi (A-error dominates either way).
__global__ __launch_bounds__(256) void k_wt(const float* __restrict__ W,
                                            hfu* __restrict__ Wt) {
  const int idx = blockIdx.x * 256 + threadIdx.x;  // (l,k,n), n fastest
  if (idx >= 3 * 256 * 256) return;
  const int n = idx & 255;
  const int k = (idx >> 8) & 255;
  const int l = idx >> 16;
  Wt[((l * 256 + n) << 8) + k] = f2h(W[idx]);
}

// ---------------------------------------------------------------------------
// fp16 MFMA GEMM (round-9 structure, single W table): C = A @ W + bias.
// Block: 64 rows x 256 cols, 4 waves (wave w owns cols [64w,64w+64)).
// A staged once to LDS via global_load_lds (inverse-swizzled source, rule 21);
// ds_read_b128 with byte ^= (row&7)<<4 kills the stride-512 bank conflict.
// Round-10 A/B test: direct-from-L2 A (no LDS) = 100us vs this structure's
// 78us at double work -> LDS staging stays. B: 4 L2 loads/ks (was 8 with
// split-W); #pragma unroll 2 overlaps next-ks B loads under MFMAs.
__global__ __launch_bounds__(256) void k_gemm_mfma(
    const hfu* __restrict__ A, const hfu* __restrict__ Wt,
    const float* __restrict__ bias, hfu* __restrict__ C) {
  __shared__ char smem[64 * 512];  // 64 rows x 256 fp16 (swizzled)
  const int t = threadIdx.x;
  const int w = t >> 6;   // wave 0..3
  const int l = t & 63;   // lane
  const int bm = blockIdx.x * 64;

  // ---- stage A rows [bm, bm+64): wave w stages rows [16w, 16w+16)
  {
    const int s = l & 31;        // 16B slot in row
    const int half = l >> 5;     // row parity within 1KB pair
#pragma unroll
    for (int i = 0; i < 8; ++i) {
      const int rb = w * 16 + i * 2;
      const int r = rb + half;
      const hfu* src = A + (size_t)(bm + r) * EMBD + ((s ^ (r & 7)) << 3);
      __builtin_amdgcn_global_load_lds(
          (const __attribute__((address_space(1))) unsigned int*)src,
          (__attribute__((address_space(3))) unsigned int*)(smem + rb * 512),
          16, 0, 0);
    }
  }
  __syncthreads();  // drains vmcnt before any wave reads LDS

  f32x4 acc[4][4];
#pragma unroll
  for (int mf = 0; mf < 4; ++mf)
#pragma unroll
    for (int nf = 0; nf < 4; ++nf) acc[mf][nf] = (f32x4)0.f;

  const int lr = l & 15;  // A-row / B-col / D-col within fragment
  const int g = l >> 4;   // k-group
  const int sw = (lr & 7) << 4;

#pragma unroll 2
  for (int ks = 0; ks < 8; ++ks) {
    const int k0 = ks * 32;
    half8v a[4], bt[4];
#pragma unroll
    for (int mf = 0; mf < 4; ++mf) {
      const int row = mf * 16 + lr;
      const int byte_ = row * 512 + (((k0 + 8 * g) * 2) ^ sw);
      a[mf] = *reinterpret_cast<const half8v*>(smem + byte_);
    }
#pragma unroll
    for (int nf = 0; nf < 4; ++nf) {
      const size_t off = (size_t)(w * 64 + nf * 16 + lr) * 256 + k0 + 8 * g;
      bt[nf] = *reinterpret_cast<const half8v*>(Wt + off);
    }
#pragma unroll
    for (int mf = 0; mf < 4; ++mf)
#pragma unroll
      for (int nf = 0; nf < 4; ++nf)
        acc[mf][nf] = __builtin_amdgcn_mfma_f32_16x16x32_f16(
            a[mf], bt[nf], acc[mf][nf], 0, 0, 0);
  }

  // ---- epilogue: D[row = mf*16 + g*4 + r][col = w*64 + nf*16 + lr] + bias
#pragma unroll
  for (int nf = 0; nf < 4; ++nf) {
    const int col = w * 64 + nf * 16 + lr;
    const float bv = bias[col];
#pragma unroll
    for (int mf = 0; mf < 4; ++mf) {
      const int r0 = bm + mf * 16 + g * 4;
#pragma unroll
      for (int r = 0; r < 4; ++r)
        st1(C + (size_t)(r0 + r) * EMBD + col, acc[mf][nf][r] + bv);
    }
  }
}

// ---------------------------------------------------------------------------
// Fused gather + update, wave per node. Per edge: one uniform 16B rec load,
// then two independent loads (combo table, hl gather).
__global__ __launch_bounds__(256) void k_gather_update(
    const int4* __restrict__ recs, const float* __restrict__ combo,
    const hfu* __restrict__ hl, const float* __restrict__ deg,
    const int* __restrict__ bcnt, const int* __restrict__ rowptr,
    const float* __restrict__ root, const float* __restrict__ gamma,
    const float* __restrict__ beta, const float* __restrict__ mean,
    const float* __restrict__ var, hfu* __restrict__ out,
    const int do_relu) {
  const int idx = blockIdx.x * 256 + threadIdx.x;
  const int n = idx >> 6;
  const int c = (idx & 63) << 2;
  const int base = rowptr[n];
  const int cnt = bcnt[n];

  float a0 = 0.f, a1 = 0.f, a2 = 0.f, a3 = 0.f;
  for (int s = 0; s < cnt; ++s) {
    const int4 rec = recs[base + s];
    const float nm = __int_as_float(rec.z);
    const float4 ee = ld4(combo + (size_t)rec.y * EMBD + c);
    const float4 hv = ld4(hl + (size_t)rec.x * EMBD + c);
    a0 += nm * fmaxf(hv.x + ee.x, 0.f);
    a1 += nm * fmaxf(hv.y + ee.y, 0.f);
    a2 += nm * fmaxf(hv.z + ee.z, 0.f);
    a3 += nm * fmaxf(hv.w + ee.w, 0.f);
  }

  const float di = 1.0f / deg[n];
  const float4 hv = ld4(hl + (size_t)n * EMBD + c);
  const float4 r = *reinterpret_cast<const float4*>(root + c);
  const float4 mn = *reinterpret_cast<const float4*>(mean + c);
  const float4 g = *reinterpret_cast<const float4*>(gamma + c);
  const float4 vv = *reinterpret_cast<const float4*>(var + c);
  const float4 bt = *reinterpret_cast<const float4*>(beta + c);
  float v0 = a0 + fmaxf(hv.x + r.x, 0.f) * di;
  float v1 = a1 + fmaxf(hv.y + r.y, 0.f) * di;
  float v2 = a2 + fmaxf(hv.z + r.z, 0.f) * di;
  float v3 = a3 + fmaxf(hv.w + r.w, 0.f) * di;
  v0 = (v0 - mn.x) * (g.x / sqrtf(vv.x + 1e-5f)) + bt.x;
  v1 = (v1 - mn.y) * (g.y / sqrtf(vv.y + 1e-5f)) + bt.y;
  v2 = (v2 - mn.z) * (g.z / sqrtf(vv.z + 1e-5f)) + bt.z;
  v3 = (v3 - mn.w) * (g.w / sqrtf(vv.w + 1e-5f)) + bt.w;
  if (do_relu) {
    v0 = fmaxf(v0, 0.f); v1 = fmaxf(v1, 0.f);
    v2 = fmaxf(v2, 0.f); v3 = fmaxf(v3, 0.f);
  }
  st4(out + (size_t)n * EMBD + c, make_float4(v0, v1, v2, v3));
}

// ---------------------------------------------------------------------------
// Pool: batch sorted -> run-length accumulate, one atomic per (run, channel).
__global__ __launch_bounds__(256) void k_pool(const hfu* __restrict__ h,
                                              const int* __restrict__ batch,
                                              float* __restrict__ out) {
  const int c = threadIdx.x;
  const int n0 = blockIdx.x * 128;
  float acc = 0.f;
  int gprev = batch[n0];
  for (int i = 0; i < 128; ++i) {
    const int n = n0 + i;
    const int g = batch[n];
    if (g != gprev) {
      atomicAdd(&out[gprev * EMBD + c], acc);
      acc = 0.f;
      gprev = g;
    }
    acc += h2f(h[(size_t)n * EMBD + c]);
  }
  atomicAdd(&out[gprev * EMBD + c], acc);
}

// ---------------------------------------------------------------------------
extern "C" void kernel_launch(void* const* d_in, const int* in_sizes, int n_in,
                              void* d_out, int out_size, void* d_ws,
                              size_t ws_size, hipStream_t stream) {
  const float* atom_emb = (const float*)d_in[0];
  const float* bond_emb = (const float*)d_in[1];
  const float* W = (const float*)d_in[2];
  const float* b = (const float*)d_in[3];
  const float* root = (const float*)d_in[4];
  const float* gamma = (const float*)d_in[5];
  const float* beta = (const float*)d_in[6];
  const float* mean = (const float*)d_in[7];
  const float* var = (const float*)d_in[8];
  const int* x = (const int*)d_in[9];
  const int* ei = (const int*)d_in[10];
  const int* ea = (const int*)d_in[11];
  const int* batch = (const int*)d_in[12];
  float* out = (float*)d_out;

  const size_t H = (size_t)NN * EMBD;  // elements per h buffer
  // ws layout: X (fp16, 67MB) | Y (fp16, 67MB) | recs (NE int4, 4MB) |
  //            combo (3*60*256 f32, 184KB)  => 138.6 MB total
  const size_t need = 2 * H * sizeof(hfu) + (size_t)NE * 16 +
                      (size_t)3 * 60 * EMBD * sizeof(float);
  if (ws_size < need) {  // fails validation cleanly instead of faulting
    k_zero<<<1024, 256, 0, stream>>>((float4*)out, NG * EMBD / 4);
    return;
  }
  char* ws = (char*)d_ws;
  hfu* X = (hfu*)ws;
  hfu* Y = X + H;
  int4* recs = (int4*)(ws + 2 * H * sizeof(hfu));
  float* combo = (float*)(recs + NE);

  // graph metadata + fp16 Wt live in d_out (4 MiB) until the final pool
  float* deg = out;                        // NN f32
  float* dnv = out + NN;                   // NN f32
  int* bcnt = (int*)(out + 2 * NN);        // NN
  int* rowptr = bcnt + NN;                 // NN
  int* ticket = rowptr + NN;               // NN  (dead after k_scatter)
  int* bsum = ticket + NN;                 // 512
  hfu* Wt = (hfu*)ticket;                  // 3*64K fp16 = 384 KB <= 512 KB

  k_zero<<<1024, 256, 0, stream>>>((float4*)out, (5 * NN + 512) / 4);
  k_atom_encode<<<NN / 4, 256, 0, stream>>>(atom_emb, x, X);
  k_count<<<NE / 256, 256, 0, stream>>>(ei, deg, bcnt);
  k_bsum<<<NN / 256, 256, 0, stream>>>(bcnt, bsum);
  k_bscan<<<1, 512, 0, stream>>>(bsum);
  k_rowptr<<<NN / 256, 256, 0, stream>>>(bcnt, bsum, rowptr);
  k_finish_deg<<<NN / 256, 256, 0, stream>>>(deg, dnv);   // before scatter
  k_scatter<<<NE / 256, 256, 0, stream>>>(ei, ea, dnv, rowptr, ticket, recs);
  k_wt<<<3 * 256 * 256 / 256, 256, 0, stream>>>(W, Wt);   // ticket dead now
  k_combo<<<(3 * 60 * 64 + 255) / 256, 256, 0, stream>>>(bond_emb, combo);

  for (int l = 0; l < 3; ++l) {
    k_gemm_mfma<<<NN / 64, 256, 0, stream>>>(
        X, Wt + l * 65536, b + l * EMBD, Y);
    k_gather_update<<<NN / 4, 256, 0, stream>>>(
        recs, combo + (size_t)l * 60 * EMBD, Y, deg, bcnt, rowptr,
        root + l * EMBD, gamma + l * EMBD, beta + l * EMBD, mean + l * EMBD,
        var + l * EMBD, X, (l < 2) ? 1 : 0);
  }
  // metadata now dead: zero the full output, then pool h3 (in X) into it
  k_zero<<<1024, 256, 0, stream>>>((float4*)out, NG * EMBD / 4);
  k_pool<<<NN / 128, 256, 0, stream>>>(X, batch, out);
}

// Round 12
// 507.904 us; speedup vs baseline: 1.4066x; 1.1464x over previous
//
#include <hip/hip_runtime.h>

#define NN 131072   // nodes
#define NE 262144   // edges
#define NG 4096     // graphs
#define EMBD 256

typedef unsigned short hfu;  // raw fp16 bits (storage only; compute f32)
typedef __attribute__((ext_vector_type(8))) _Float16 half8v;  // MFMA A/B frag
typedef __attribute__((ext_vector_type(4))) float f32x4;      // MFMA C/D frag

__device__ __forceinline__ float h2f(hfu u) {
  _Float16 h = *reinterpret_cast<const _Float16*>(&u);
  return (float)h;
}
__device__ __forceinline__ hfu f2h(float f) {  // RTE via v_cvt_f16_f32
  _Float16 h = (_Float16)f;
  return *reinterpret_cast<const hfu*>(&h);
}
__device__ __forceinline__ float4 ld4(const float* p) {
  return *reinterpret_cast<const float4*>(p);
}
__device__ __forceinline__ float4 ld4(const hfu* p) {
  ushort4 u = *reinterpret_cast<const ushort4*>(p);
  return make_float4(h2f(u.x), h2f(u.y), h2f(u.z), h2f(u.w));
}
__device__ __forceinline__ void st4(float* p, float4 v) {
  *reinterpret_cast<float4*>(p) = v;
}
__device__ __forceinline__ void st4(hfu* p, float4 v) {
  *reinterpret_cast<ushort4*>(p) =
      make_ushort4(f2h(v.x), f2h(v.y), f2h(v.z), f2h(v.w));
}
__device__ __forceinline__ void st1(hfu* p, float v) { *p = f2h(v); }

// ---------------------------------------------------------------------------
__global__ __launch_bounds__(256) void k_zero(float4* p, int n4) {
  for (int i = blockIdx.x * 256 + threadIdx.x; i < n4; i += gridDim.x * 256)
    p[i] = make_float4(0.f, 0.f, 0.f, 0.f);
}

// ---------------------------------------------------------------------------
// Atom encoder: h[n][c] = sum_f atom_emb[x[n][f] + off[f]][c]. Wave = node.
__global__ __launch_bounds__(256) void k_atom_encode(
    const float* __restrict__ atom_emb, const int* __restrict__ x,
    hfu* __restrict__ h) {
  const int idx = blockIdx.x * 256 + threadIdx.x;
  const int n = idx >> 6;
  const int c = (idx & 63) << 2;
  const int off[9] = {0, 119, 123, 135, 147, 157, 163, 168, 170};
  const int* xr = x + n * 9;
  float4 acc = make_float4(0.f, 0.f, 0.f, 0.f);
#pragma unroll
  for (int f = 0; f < 9; ++f) {
    const float4 v =
        *reinterpret_cast<const float4*>(atom_emb + (xr[f] + off[f]) * EMBD + c);
    acc.x += v.x; acc.y += v.y; acc.z += v.z; acc.w += v.w;
  }
  st4(h + (size_t)n * EMBD + c, acc);
}

// ---------------------------------------------------------------------------
// CSR build over destinations + source-degree count.
__global__ __launch_bounds__(256) void k_count(const int* __restrict__ ei,
                                               float* __restrict__ deg,
                                               int* __restrict__ bcnt) {
  const int e = blockIdx.x * 256 + threadIdx.x;
  if (e >= NE) return;
  atomicAdd(&deg[ei[e]], 1.0f);
  atomicAdd(&bcnt[ei[NE + e]], 1);
}

__global__ __launch_bounds__(256) void k_bsum(const int* __restrict__ bcnt,
                                              int* __restrict__ bsum) {
  __shared__ int s[256];
  const int t = threadIdx.x;
  s[t] = bcnt[blockIdx.x * 256 + t];
  __syncthreads();
  for (int o = 128; o; o >>= 1) {
    if (t < o) s[t] += s[t + o];
    __syncthreads();
  }
  if (t == 0) bsum[blockIdx.x] = s[0];
}

__global__ __launch_bounds__(512) void k_bscan(int* __restrict__ bsum) {
  __shared__ int s[512];
  const int t = threadIdx.x;
  s[t] = bsum[t];
  __syncthreads();
  for (int o = 1; o < 512; o <<= 1) {
    const int v = (t >= o) ? s[t - o] : 0;
    __syncthreads();
    s[t] += v;
    __syncthreads();
  }
  bsum[t] = t ? s[t - 1] : 0;  // exclusive
}

__global__ __launch_bounds__(256) void k_rowptr(const int* __restrict__ bcnt,
                                                const int* __restrict__ bsum,
                                                int* __restrict__ rowptr) {
  __shared__ int s[256];
  const int t = threadIdx.x;
  const int n = blockIdx.x * 256 + t;
  s[t] = bcnt[n];
  __syncthreads();
  for (int o = 1; o < 256; o <<= 1) {
    const int v = (t >= o) ? s[t - o] : 0;
    __syncthreads();
    s[t] += v;
    __syncthreads();
  }
  rowptr[n] = bsum[blockIdx.x] + (t ? s[t - 1] : 0);
}

__global__ __launch_bounds__(256) void k_finish_deg(float* __restrict__ deg,
                                                    float* __restrict__ dinv) {
  const int n = blockIdx.x * 256 + threadIdx.x;
  const float d = deg[n] + 1.0f;
  deg[n] = d;
  dinv[n] = 1.0f / sqrtf(d);
}

// ---------------------------------------------------------------------------
// Scatter edges into CSR slots as packed records {row, combo, norm} (16 B).
__global__ __launch_bounds__(256) void k_scatter(const int* __restrict__ ei,
                                                 const int* __restrict__ ea,
                                                 const float* __restrict__ dinv,
                                                 const int* __restrict__ rowptr,
                                                 int* __restrict__ ticket,
                                                 int4* __restrict__ recs) {
  const int e = blockIdx.x * 256 + threadIdx.x;
  if (e >= NE) return;
  const int row = ei[e];
  const int col = ei[NE + e];
  const int slot = atomicAdd(&ticket[col], 1);
  const int combo = ea[e * 3] * 12 + ea[e * 3 + 1] * 2 + ea[e * 3 + 2];
  const float nm = dinv[row] * dinv[col];
  recs[rowptr[col] + slot] =
      make_int4(row, combo, __float_as_int(nm), 0);
}

// ---------------------------------------------------------------------------
// Pre-sum the 60 possible bond-embedding combinations per layer (184 KB).
__global__ __launch_bounds__(256) void k_combo(const float* __restrict__ bond,
                                               float* __restrict__ combo) {
  const int idx = blockIdx.x * 256 + threadIdx.x;  // (l, cmb, lane)
  if (idx >= 3 * 60 * 64) return;
  const int c = (idx & 63) << 2;
  const int cmb = (idx >> 6) % 60;
  const int l = idx / (60 * 64);
  const int a0 = cmb / 12, a1 = (cmb % 12) / 2, a2 = cmb & 1;
  const float* bl = bond + l * 13 * EMBD;
  const float4 b0 = ld4(bl + a0 * EMBD + c);
  const float4 b1 = ld4(bl + (5 + a1) * EMBD + c);
  const float4 b2 = ld4(bl + (11 + a2) * EMBD + c);
  st4(combo + ((size_t)(l * 60 + cmb)) * EMBD + c,
      make_float4(b0.x + b1.x + b2.x, b0.y + b1.y + b2.y,
                  b0.z + b1.z + b2.z, b0.w + b1.w + b2.w));
}

// ---------------------------------------------------------------------------
// BN fold: scale[l][c] = gamma*rsqrt(var+eps); shift = beta - mean*scale.
// Removes 4x sqrt + 4x div + 3 loads per lane from the gather epilogue.
__global__ __launch_bounds__(256) void k_bnparam(
    const float* __restrict__ gamma, const float* __restrict__ beta,
    const float* __restrict__ mean, const float* __restrict__ var,
    float* __restrict__ scale, float* __restrict__ shift) {
  const int i = blockIdx.x * 256 + threadIdx.x;  // 3*256
  if (i >= 3 * EMBD) return;
  const float sc = gamma[i] * rsqrtf(var[i] + 1e-5f);
  scale[i] = sc;
  shift[i] = beta[i] - mean[i] * sc;
}

// ---------------------------------------------------------------------------
// W transpose to fp16: Wt[l][n][k] = fp16(W[l][k][n]).
__global__ __launch_bounds__(256) void k_wt(const float* __restrict__ W,
                                            hfu* __restrict__ Wt) {
  const int idx = blockIdx.x * 256 + threadIdx.x;  // (l,k,n), n fastest
  if (idx >= 3 * 256 * 256) return;
  const int n = idx & 255;
  const int k = (idx >> 8) & 255;
  const int l = idx >> 16;
  Wt[((l * 256 + n) << 8) + k] = f2h(W[idx]);
}

// ---------------------------------------------------------------------------
// fp16 MFMA GEMM (round-9 structure, single W table): C = A @ W + bias.
// A staged once to LDS via global_load_lds (inverse-swizzled source, rule 21);
// ds_read_b128 with byte ^= (row&7)<<4 kills the stride-512 bank conflict.
// Round-10 A/B: direct-from-L2 A (no LDS) regressed 78->100us; LDS stays.
__global__ __launch_bounds__(256) void k_gemm_mfma(
    const hfu* __restrict__ A, const hfu* __restrict__ Wt,
    const float* __restrict__ bias, hfu* __restrict__ C) {
  __shared__ char smem[64 * 512];  // 64 rows x 256 fp16 (swizzled)
  const int t = threadIdx.x;
  const int w = t >> 6;   // wave 0..3
  const int l = t & 63;   // lane
  const int bm = blockIdx.x * 64;

  {
    const int s = l & 31;        // 16B slot in row
    const int half = l >> 5;     // row parity within 1KB pair
#pragma unroll
    for (int i = 0; i < 8; ++i) {
      const int rb = w * 16 + i * 2;
      const int r = rb + half;
      const hfu* src = A + (size_t)(bm + r) * EMBD + ((s ^ (r & 7)) << 3);
      __builtin_amdgcn_global_load_lds(
          (const __attribute__((address_space(1))) unsigned int*)src,
          (__attribute__((address_space(3))) unsigned int*)(smem + rb * 512),
          16, 0, 0);
    }
  }
  __syncthreads();  // drains vmcnt before any wave reads LDS

  f32x4 acc[4][4];
#pragma unroll
  for (int mf = 0; mf < 4; ++mf)
#pragma unroll
    for (int nf = 0; nf < 4; ++nf) acc[mf][nf] = (f32x4)0.f;

  const int lr = l & 15;  // A-row / B-col / D-col within fragment
  const int g = l >> 4;   // k-group
  const int sw = (lr & 7) << 4;

#pragma unroll 2
  for (int ks = 0; ks < 8; ++ks) {
    const int k0 = ks * 32;
    half8v a[4], bt[4];
#pragma unroll
    for (int mf = 0; mf < 4; ++mf) {
      const int row = mf * 16 + lr;
      const int byte_ = row * 512 + (((k0 + 8 * g) * 2) ^ sw);
      a[mf] = *reinterpret_cast<const half8v*>(smem + byte_);
    }
#pragma unroll
    for (int nf = 0; nf < 4; ++nf) {
      const size_t off = (size_t)(w * 64 + nf * 16 + lr) * 256 + k0 + 8 * g;
      bt[nf] = *reinterpret_cast<const half8v*>(Wt + off);
    }
#pragma unroll
    for (int mf = 0; mf < 4; ++mf)
#pragma unroll
      for (int nf = 0; nf < 4; ++nf)
        acc[mf][nf] = __builtin_amdgcn_mfma_f32_16x16x32_f16(
            a[mf], bt[nf], acc[mf][nf], 0, 0, 0);
  }

  // ---- epilogue: D[row = mf*16 + g*4 + r][col = w*64 + nf*16 + lr] + bias
#pragma unroll
  for (int nf = 0; nf < 4; ++nf) {
    const int col = w * 64 + nf * 16 + lr;
    const float bv = bias[col];
#pragma unroll
    for (int mf = 0; mf < 4; ++mf) {
      const int r0 = bm + mf * 16 + g * 4;
#pragma unroll
      for (int r = 0; r < 4; ++r)
        st1(C + (size_t)(r0 + r) * EMBD + col, acc[mf][nf][r] + bv);
    }
  }
}

// ---------------------------------------------------------------------------
// Fused gather + update, wave per node. Round-11 PMC: VALUBusy 67%, HBM 28%,
// VGPR 28 -> dependent-load latency-bound. Fixes: (1) wave-uniform n via
// readfirstlane -> rowptr/bcnt/rec addressing on the scalar path; (2) 2-edge
// software pipeline (independent accumulator pairs) halves serial latency
// round-trips at avg in-degree 2; (3) BN scale/shift + dinv^2 strip the
// sqrt/div chain and 3 loads from the epilogue.
__global__ __launch_bounds__(256) void k_gather_update(
    const int4* __restrict__ recs, const float* __restrict__ combo,
    const hfu* __restrict__ hl, const float* __restrict__ dinv,
    const int* __restrict__ bcnt, const int* __restrict__ rowptr,
    const float* __restrict__ root, const float* __restrict__ scale,
    const float* __restrict__ shift, hfu* __restrict__ out,
    const int do_relu) {
  const int idx = blockIdx.x * 256 + threadIdx.x;
  const int n = __builtin_amdgcn_readfirstlane(idx >> 6);  // wave-uniform
  const int c = (idx & 63) << 2;
  const int base = rowptr[n];
  const int cnt = bcnt[n];

  float a0 = 0.f, a1 = 0.f, a2 = 0.f, a3 = 0.f;
  float b0 = 0.f, b1 = 0.f, b2 = 0.f, b3 = 0.f;
  int s = 0;
  for (; s + 2 <= cnt; s += 2) {
    const int4 r0 = recs[base + s];
    const int4 r1 = recs[base + s + 1];
    const float nm0 = __int_as_float(r0.z);
    const float nm1 = __int_as_float(r1.z);
    const float4 e0 = ld4(combo + (size_t)r0.y * EMBD + c);
    const float4 h0 = ld4(hl + (size_t)r0.x * EMBD + c);
    const float4 e1 = ld4(combo + (size_t)r1.y * EMBD + c);
    const float4 h1 = ld4(hl + (size_t)r1.x * EMBD + c);
    a0 += nm0 * fmaxf(h0.x + e0.x, 0.f);
    a1 += nm0 * fmaxf(h0.y + e0.y, 0.f);
    a2 += nm0 * fmaxf(h0.z + e0.z, 0.f);
    a3 += nm0 * fmaxf(h0.w + e0.w, 0.f);
    b0 += nm1 * fmaxf(h1.x + e1.x, 0.f);
    b1 += nm1 * fmaxf(h1.y + e1.y, 0.f);
    b2 += nm1 * fmaxf(h1.z + e1.z, 0.f);
    b3 += nm1 * fmaxf(h1.w + e1.w, 0.f);
  }
  if (s < cnt) {
    const int4 r0 = recs[base + s];
    const float nm0 = __int_as_float(r0.z);
    const float4 e0 = ld4(combo + (size_t)r0.y * EMBD + c);
    const float4 h0 = ld4(hl + (size_t)r0.x * EMBD + c);
    a0 += nm0 * fmaxf(h0.x + e0.x, 0.f);
    a1 += nm0 * fmaxf(h0.y + e0.y, 0.f);
    a2 += nm0 * fmaxf(h0.z + e0.z, 0.f);
    a3 += nm0 * fmaxf(h0.w + e0.w, 0.f);
  }
  a0 += b0; a1 += b1; a2 += b2; a3 += b3;

  const float dn = dinv[n];
  const float di = dn * dn;  // == 1/deg
  const float4 hv = ld4(hl + (size_t)n * EMBD + c);
  const float4 r = ld4(root + c);
  const float4 sc = ld4(scale + c);
  const float4 sh = ld4(shift + c);
  float v0 = fmaf(fmaxf(hv.x + r.x, 0.f), di, a0);
  float v1 = fmaf(fmaxf(hv.y + r.y, 0.f), di, a1);
  float v2 = fmaf(fmaxf(hv.z + r.z, 0.f), di, a2);
  float v3 = fmaf(fmaxf(hv.w + r.w, 0.f), di, a3);
  v0 = fmaf(v0, sc.x, sh.x);
  v1 = fmaf(v1, sc.y, sh.y);
  v2 = fmaf(v2, sc.z, sh.z);
  v3 = fmaf(v3, sc.w, sh.w);
  if (do_relu) {
    v0 = fmaxf(v0, 0.f); v1 = fmaxf(v1, 0.f);
    v2 = fmaxf(v2, 0.f); v3 = fmaxf(v3, 0.f);
  }
  st4(out + (size_t)n * EMBD + c, make_float4(v0, v1, v2, v3));
}

// ---------------------------------------------------------------------------
// Pool: batch sorted -> run-length accumulate, one atomic per (run, channel).
__global__ __launch_bounds__(256) void k_pool(const hfu* __restrict__ h,
                                              const int* __restrict__ batch,
                                              float* __restrict__ out) {
  const int c = threadIdx.x;
  const int n0 = blockIdx.x * 128;
  float acc = 0.f;
  int gprev = batch[n0];
  for (int i = 0; i < 128; ++i) {
    const int n = n0 + i;
    const int g = batch[n];
    if (g != gprev) {
      atomicAdd(&out[gprev * EMBD + c], acc);
      acc = 0.f;
      gprev = g;
    }
    acc += h2f(h[(size_t)n * EMBD + c]);
  }
  atomicAdd(&out[gprev * EMBD + c], acc);
}

// ---------------------------------------------------------------------------
extern "C" void kernel_launch(void* const* d_in, const int* in_sizes, int n_in,
                              void* d_out, int out_size, void* d_ws,
                              size_t ws_size, hipStream_t stream) {
  const float* atom_emb = (const float*)d_in[0];
  const float* bond_emb = (const float*)d_in[1];
  const float* W = (const float*)d_in[2];
  const float* b = (const float*)d_in[3];
  const float* root = (const float*)d_in[4];
  const float* gamma = (const float*)d_in[5];
  const float* beta = (const float*)d_in[6];
  const float* mean = (const float*)d_in[7];
  const float* var = (const float*)d_in[8];
  const int* x = (const int*)d_in[9];
  const int* ei = (const int*)d_in[10];
  const int* ea = (const int*)d_in[11];
  const int* batch = (const int*)d_in[12];
  float* out = (float*)d_out;

  const size_t H = (size_t)NN * EMBD;  // elements per h buffer
  // ws layout: X (fp16, 67MB) | Y (fp16, 67MB) | recs (NE int4, 4MB) |
  //            combo (3*60*256 f32, 184KB) | bnscale/bnshift (6KB)
  const size_t need = 2 * H * sizeof(hfu) + (size_t)NE * 16 +
                      (size_t)3 * 60 * EMBD * sizeof(float) +
                      2 * 3 * EMBD * sizeof(float);
  if (ws_size < need) {  // fails validation cleanly instead of faulting
    k_zero<<<1024, 256, 0, stream>>>((float4*)out, NG * EMBD / 4);
    return;
  }
  char* ws = (char*)d_ws;
  hfu* X = (hfu*)ws;
  hfu* Y = X + H;
  int4* recs = (int4*)(ws + 2 * H * sizeof(hfu));
  float* combo = (float*)(recs + NE);
  float* bnscale = combo + (size_t)3 * 60 * EMBD;
  float* bnshift = bnscale + 3 * EMBD;

  // graph metadata + fp16 Wt live in d_out (4 MiB) until the final pool
  float* deg = out;                        // NN f32
  float* dnv = out + NN;                   // NN f32
  int* bcnt = (int*)(out + 2 * NN);        // NN
  int* rowptr = bcnt + NN;                 // NN
  int* ticket = rowptr + NN;               // NN  (dead after k_scatter)
  int* bsum = ticket + NN;                 // 512
  hfu* Wt = (hfu*)ticket;                  // 3*64K fp16 = 384 KB <= 512 KB

  k_zero<<<1024, 256, 0, stream>>>((float4*)out, (5 * NN + 512) / 4);
  k_atom_encode<<<NN / 4, 256, 0, stream>>>(atom_emb, x, X);
  k_count<<<NE / 256, 256, 0, stream>>>(ei, deg, bcnt);
  k_bsum<<<NN / 256, 256, 0, stream>>>(bcnt, bsum);
  k_bscan<<<1, 512, 0, stream>>>(bsum);
  k_rowptr<<<NN / 256, 256, 0, stream>>>(bcnt, bsum, rowptr);
  k_finish_deg<<<NN / 256, 256, 0, stream>>>(deg, dnv);   // before scatter
  k_scatter<<<NE / 256, 256, 0, stream>>>(ei, ea, dnv, rowptr, ticket, recs);
  k_wt<<<3 * 256 * 256 / 256, 256, 0, stream>>>(W, Wt);   // ticket dead now
  k_combo<<<(3 * 60 * 64 + 255) / 256, 256, 0, stream>>>(bond_emb, combo);
  k_bnparam<<<3, 256, 0, stream>>>(gamma, beta, mean, var, bnscale, bnshift);

  for (int l = 0; l < 3; ++l) {
    k_gemm_mfma<<<NN / 64, 256, 0, stream>>>(
        X, Wt + l * 65536, b + l * EMBD, Y);
    k_gather_update<<<NN / 4, 256, 0, stream>>>(
        recs, combo + (size_t)l * 60 * EMBD, Y, dnv, bcnt, rowptr,
        root + l * EMBD, bnscale + l * EMBD, bnshift + l * EMBD, X,
        (l < 2) ? 1 : 0);
  }
  // metadata now dead: zero the full output, then pool h3 (in X) into it
  k_zero<<<1024, 256, 0, stream>>>((float4*)out, NG * EMBD / 4);
  k_pool<<<NN / 128, 256, 0, stream>>>(X, batch, out);
}

// Round 13
// 491.825 us; speedup vs baseline: 1.4526x; 1.0327x over previous
//
#include <hip/hip_runtime.h>

#define NN 131072   // nodes
#define NE 262144   // edges
#define NG 4096     // graphs
#define EMBD 256

typedef unsigned short hfu;  // raw fp16 bits (storage only; compute f32)
typedef __attribute__((ext_vector_type(8))) _Float16 half8v;  // MFMA A/B frag
typedef __attribute__((ext_vector_type(4))) float f32x4;      // MFMA C/D frag

__device__ __forceinline__ float h2f(hfu u) {
  _Float16 h = *reinterpret_cast<const _Float16*>(&u);
  return (float)h;
}
__device__ __forceinline__ hfu f2h(float f) {  // RTE via v_cvt_f16_f32
  _Float16 h = (_Float16)f;
  return *reinterpret_cast<const hfu*>(&h);
}
__device__ __forceinline__ float4 ld4(const float* p) {
  return *reinterpret_cast<const float4*>(p);
}
__device__ __forceinline__ float4 ld4(const hfu* p) {
  ushort4 u = *reinterpret_cast<const ushort4*>(p);
  return make_float4(h2f(u.x), h2f(u.y), h2f(u.z), h2f(u.w));
}
__device__ __forceinline__ void st4(float* p, float4 v) {
  *reinterpret_cast<float4*>(p) = v;
}
__device__ __forceinline__ void st4(hfu* p, float4 v) {
  *reinterpret_cast<ushort4*>(p) =
      make_ushort4(f2h(v.x), f2h(v.y), f2h(v.z), f2h(v.w));
}
__device__ __forceinline__ void st1(hfu* p, float v) { *p = f2h(v); }

// ---------------------------------------------------------------------------
__global__ __launch_bounds__(256) void k_zero(float4* p, int n4) {
  for (int i = blockIdx.x * 256 + threadIdx.x; i < n4; i += gridDim.x * 256)
    p[i] = make_float4(0.f, 0.f, 0.f, 0.f);
}

// ---------------------------------------------------------------------------
// Atom encoder: h[n][c] = sum_f atom_emb[x[n][f] + off[f]][c]. Wave = node;
// row indices are wave-uniform -> readfirstlane puts them on the scalar path.
__global__ __launch_bounds__(256) void k_atom_encode(
    const float* __restrict__ atom_emb, const int* __restrict__ x,
    hfu* __restrict__ h) {
  const int idx = blockIdx.x * 256 + threadIdx.x;
  const int n = idx >> 6;
  const int c = (idx & 63) << 2;
  const int off[9] = {0, 119, 123, 135, 147, 157, 163, 168, 170};
  const int* xr = x + n * 9;
  float4 acc = make_float4(0.f, 0.f, 0.f, 0.f);
#pragma unroll
  for (int f = 0; f < 9; ++f) {
    const int row = __builtin_amdgcn_readfirstlane(xr[f] + off[f]);
    const float4 v = *reinterpret_cast<const float4*>(atom_emb + row * EMBD + c);
    acc.x += v.x; acc.y += v.y; acc.z += v.z; acc.w += v.w;
  }
  st4(h + (size_t)n * EMBD + c, acc);
}

// ---------------------------------------------------------------------------
// CSR build over destinations + source-degree count.
__global__ __launch_bounds__(256) void k_count(const int* __restrict__ ei,
                                               float* __restrict__ deg,
                                               int* __restrict__ bcnt) {
  const int e = blockIdx.x * 256 + threadIdx.x;
  if (e >= NE) return;
  atomicAdd(&deg[ei[e]], 1.0f);
  atomicAdd(&bcnt[ei[NE + e]], 1);
}

__global__ __launch_bounds__(256) void k_bsum(const int* __restrict__ bcnt,
                                              int* __restrict__ bsum) {
  __shared__ int s[256];
  const int t = threadIdx.x;
  s[t] = bcnt[blockIdx.x * 256 + t];
  __syncthreads();
  for (int o = 128; o; o >>= 1) {
    if (t < o) s[t] += s[t + o];
    __syncthreads();
  }
  if (t == 0) bsum[blockIdx.x] = s[0];
}

__global__ __launch_bounds__(512) void k_bscan(int* __restrict__ bsum) {
  __shared__ int s[512];
  const int t = threadIdx.x;
  s[t] = bsum[t];
  __syncthreads();
  for (int o = 1; o < 512; o <<= 1) {
    const int v = (t >= o) ? s[t - o] : 0;
    __syncthreads();
    s[t] += v;
    __syncthreads();
  }
  bsum[t] = t ? s[t - 1] : 0;  // exclusive
}

__global__ __launch_bounds__(256) void k_rowptr(const int* __restrict__ bcnt,
                                                const int* __restrict__ bsum,
                                                int* __restrict__ rowptr) {
  __shared__ int s[256];
  const int t = threadIdx.x;
  const int n = blockIdx.x * 256 + t;
  s[t] = bcnt[n];
  __syncthreads();
  for (int o = 1; o < 256; o <<= 1) {
    const int v = (t >= o) ? s[t - o] : 0;
    __syncthreads();
    s[t] += v;
    __syncthreads();
  }
  rowptr[n] = bsum[blockIdx.x] + (t ? s[t - 1] : 0);
}

__global__ __launch_bounds__(256) void k_finish_deg(float* __restrict__ deg,
                                                    float* __restrict__ dinv) {
  const int n = blockIdx.x * 256 + threadIdx.x;
  const float d = deg[n] + 1.0f;
  deg[n] = d;
  dinv[n] = 1.0f / sqrtf(d);
}

// ---------------------------------------------------------------------------
// Scatter edges into CSR slots as packed records {row, combo, norm} (16 B).
__global__ __launch_bounds__(256) void k_scatter(const int* __restrict__ ei,
                                                 const int* __restrict__ ea,
                                                 const float* __restrict__ dinv,
                                                 const int* __restrict__ rowptr,
                                                 int* __restrict__ ticket,
                                                 int4* __restrict__ recs) {
  const int e = blockIdx.x * 256 + threadIdx.x;
  if (e >= NE) return;
  const int row = ei[e];
  const int col = ei[NE + e];
  const int slot = atomicAdd(&ticket[col], 1);
  const int combo = ea[e * 3] * 12 + ea[e * 3 + 1] * 2 + ea[e * 3 + 2];
  const float nm = dinv[row] * dinv[col];
  recs[rowptr[col] + slot] =
      make_int4(row, combo, __float_as_int(nm), 0);
}

// ---------------------------------------------------------------------------
// Pre-sum the 60 possible bond-embedding combinations per layer (184 KB).
__global__ __launch_bounds__(256) void k_combo(const float* __restrict__ bond,
                                               float* __restrict__ combo) {
  const int idx = blockIdx.x * 256 + threadIdx.x;  // (l, cmb, lane)
  if (idx >= 3 * 60 * 64) return;
  const int c = (idx & 63) << 2;
  const int cmb = (idx >> 6) % 60;
  const int l = idx / (60 * 64);
  const int a0 = cmb / 12, a1 = (cmb % 12) / 2, a2 = cmb & 1;
  const float* bl = bond + l * 13 * EMBD;
  const float4 b0 = ld4(bl + a0 * EMBD + c);
  const float4 b1 = ld4(bl + (5 + a1) * EMBD + c);
  const float4 b2 = ld4(bl + (11 + a2) * EMBD + c);
  st4(combo + ((size_t)(l * 60 + cmb)) * EMBD + c,
      make_float4(b0.x + b1.x + b2.x, b0.y + b1.y + b2.y,
                  b0.z + b1.z + b2.z, b0.w + b1.w + b2.w));
}

// ---------------------------------------------------------------------------
// BN fold: scale[l][c] = gamma*rsqrt(var+eps); shift = beta - mean*scale.
__global__ __launch_bounds__(256) void k_bnparam(
    const float* __restrict__ gamma, const float* __restrict__ beta,
    const float* __restrict__ mean, const float* __restrict__ var,
    float* __restrict__ scale, float* __restrict__ shift) {
  const int i = blockIdx.x * 256 + threadIdx.x;  // 3*256
  if (i >= 3 * EMBD) return;
  const float sc = gamma[i] * rsqrtf(var[i] + 1e-5f);
  scale[i] = sc;
  shift[i] = beta[i] - mean[i] * sc;
}

// ---------------------------------------------------------------------------
// W transpose to fp16: Wt[l][n][k] = fp16(W[l][k][n]).
__global__ __launch_bounds__(256) void k_wt(const float* __restrict__ W,
                                            hfu* __restrict__ Wt) {
  const int idx = blockIdx.x * 256 + threadIdx.x;  // (l,k,n), n fastest
  if (idx >= 3 * 256 * 256) return;
  const int n = idx & 255;
  const int k = (idx >> 8) & 255;
  const int l = idx >> 16;
  Wt[((l * 256 + n) << 8) + k] = f2h(W[idx]);
}

// ---------------------------------------------------------------------------
// fp16 MFMA GEMM: C = A @ W + bias. Round-12 PMC: MfmaUtil 11.5%, nothing
// saturated -> latency-bound on the 4 per-ks L2 B-loads. Fix: hoist ALL 32
// B-frags (512 B/lane = 128 VGPR) into registers before a fully-unrolled
// K-loop (static indexing, rule 20) -> one up-front load burst, inner loop
// is pure ds_read+MFMA. acc 64 + B 128 + A 16 VGPR -> ~228, cap 256 via
// __launch_bounds__(256,2). A staged via global_load_lds w/ XOR swizzle
// (round-10 A/B: removing LDS staging regressed 78->100us, it stays).
__global__ __launch_bounds__(256, 2) void k_gemm_mfma(
    const hfu* __restrict__ A, const hfu* __restrict__ Wt,
    const float* __restrict__ bias, hfu* __restrict__ C) {
  __shared__ char smem[64 * 512];  // 64 rows x 256 fp16 (swizzled)
  const int t = threadIdx.x;
  const int w = t >> 6;   // wave 0..3
  const int l = t & 63;   // lane
  const int bm = blockIdx.x * 64;
  const int lr = l & 15;  // A-row / B-col / D-col within fragment
  const int g = l >> 4;   // k-group
  const int sw = (lr & 7) << 4;

  // ---- stage A rows [bm, bm+64): wave w stages rows [16w, 16w+16)
  {
    const int s = l & 31;        // 16B slot in row
    const int half = l >> 5;     // row parity within 1KB pair
#pragma unroll
    for (int i = 0; i < 8; ++i) {
      const int rb = w * 16 + i * 2;
      const int r = rb + half;
      const hfu* src = A + (size_t)(bm + r) * EMBD + ((s ^ (r & 7)) << 3);
      __builtin_amdgcn_global_load_lds(
          (const __attribute__((address_space(1))) unsigned int*)src,
          (__attribute__((address_space(3))) unsigned int*)(smem + rb * 512),
          16, 0, 0);
    }
  }

  // ---- hoist all B fragments into registers (32 x 16B, L2-hot Wt)
  half8v bt[8][4];
  {
    const hfu* brow = Wt + (size_t)(w * 64 + lr) * EMBD + 8 * g;
#pragma unroll
    for (int ks = 0; ks < 8; ++ks)
#pragma unroll
      for (int nf = 0; nf < 4; ++nf)
        bt[ks][nf] = *reinterpret_cast<const half8v*>(
            brow + nf * 16 * EMBD + ks * 32);
  }
  __syncthreads();  // drains vmcnt (A staging) before any wave reads LDS

  f32x4 acc[4][4];
#pragma unroll
  for (int mf = 0; mf < 4; ++mf)
#pragma unroll
    for (int nf = 0; nf < 4; ++nf) acc[mf][nf] = (f32x4)0.f;

#pragma unroll
  for (int ks = 0; ks < 8; ++ks) {
    const int k0 = ks * 32;
    half8v a[4];
#pragma unroll
    for (int mf = 0; mf < 4; ++mf) {
      const int row = mf * 16 + lr;
      const int byte_ = row * 512 + (((k0 + 8 * g) * 2) ^ sw);
      a[mf] = *reinterpret_cast<const half8v*>(smem + byte_);
    }
#pragma unroll
    for (int mf = 0; mf < 4; ++mf)
#pragma unroll
      for (int nf = 0; nf < 4; ++nf)
        acc[mf][nf] = __builtin_amdgcn_mfma_f32_16x16x32_f16(
            a[mf], bt[ks][nf], acc[mf][nf], 0, 0, 0);
  }

  // ---- epilogue: D[row = mf*16 + g*4 + r][col = w*64 + nf*16 + lr] + bias
#pragma unroll
  for (int nf = 0; nf < 4; ++nf) {
    const int col = w * 64 + nf * 16 + lr;
    const float bv = bias[col];
#pragma unroll
    for (int mf = 0; mf < 4; ++mf) {
      const int r0 = bm + mf * 16 + g * 4;
#pragma unroll
      for (int r = 0; r < 4; ++r)
        st1(C + (size_t)(r0 + r) * EMBD + col, acc[mf][nf][r] + bv);
    }
  }
}

// ---------------------------------------------------------------------------
// Fused gather + update, wave per node (round-12 structure: scalar n, 2-edge
// software pipeline, folded BN).
__global__ __launch_bounds__(256) void k_gather_update(
    const int4* __restrict__ recs, const float* __restrict__ combo,
    const hfu* __restrict__ hl, const float* __restrict__ dinv,
    const int* __restrict__ bcnt, const int* __restrict__ rowptr,
    const float* __restrict__ root, const float* __restrict__ scale,
    const float* __restrict__ shift, hfu* __restrict__ out,
    const int do_relu) {
  const int idx = blockIdx.x * 256 + threadIdx.x;
  const int n = __builtin_amdgcn_readfirstlane(idx >> 6);  // wave-uniform
  const int c = (idx & 63) << 2;
  const int base = rowptr[n];
  const int cnt = bcnt[n];

  float a0 = 0.f, a1 = 0.f, a2 = 0.f, a3 = 0.f;
  float b0 = 0.f, b1 = 0.f, b2 = 0.f, b3 = 0.f;
  int s = 0;
  for (; s + 2 <= cnt; s += 2) {
    const int4 r0 = recs[base + s];
    const int4 r1 = recs[base + s + 1];
    const float nm0 = __int_as_float(r0.z);
    const float nm1 = __int_as_float(r1.z);
    const float4 e0 = ld4(combo + (size_t)r0.y * EMBD + c);
    const float4 h0 = ld4(hl + (size_t)r0.x * EMBD + c);
    const float4 e1 = ld4(combo + (size_t)r1.y * EMBD + c);
    const float4 h1 = ld4(hl + (size_t)r1.x * EMBD + c);
    a0 += nm0 * fmaxf(h0.x + e0.x, 0.f);
    a1 += nm0 * fmaxf(h0.y + e0.y, 0.f);
    a2 += nm0 * fmaxf(h0.z + e0.z, 0.f);
    a3 += nm0 * fmaxf(h0.w + e0.w, 0.f);
    b0 += nm1 * fmaxf(h1.x + e1.x, 0.f);
    b1 += nm1 * fmaxf(h1.y + e1.y, 0.f);
    b2 += nm1 * fmaxf(h1.z + e1.z, 0.f);
    b3 += nm1 * fmaxf(h1.w + e1.w, 0.f);
  }
  if (s < cnt) {
    const int4 r0 = recs[base + s];
    const float nm0 = __int_as_float(r0.z);
    const float4 e0 = ld4(combo + (size_t)r0.y * EMBD + c);
    const float4 h0 = ld4(hl + (size_t)r0.x * EMBD + c);
    a0 += nm0 * fmaxf(h0.x + e0.x, 0.f);
    a1 += nm0 * fmaxf(h0.y + e0.y, 0.f);
    a2 += nm0 * fmaxf(h0.z + e0.z, 0.f);
    a3 += nm0 * fmaxf(h0.w + e0.w, 0.f);
  }
  a0 += b0; a1 += b1; a2 += b2; a3 += b3;

  const float dn = dinv[n];
  const float di = dn * dn;  // == 1/deg
  const float4 hv = ld4(hl + (size_t)n * EMBD + c);
  const float4 r = ld4(root + c);
  const float4 sc = ld4(scale + c);
  const float4 sh = ld4(shift + c);
  float v0 = fmaf(fmaxf(hv.x + r.x, 0.f), di, a0);
  float v1 = fmaf(fmaxf(hv.y + r.y, 0.f), di, a1);
  float v2 = fmaf(fmaxf(hv.z + r.z, 0.f), di, a2);
  float v3 = fmaf(fmaxf(hv.w + r.w, 0.f), di, a3);
  v0 = fmaf(v0, sc.x, sh.x);
  v1 = fmaf(v1, sc.y, sh.y);
  v2 = fmaf(v2, sc.z, sh.z);
  v3 = fmaf(v3, sc.w, sh.w);
  if (do_relu) {
    v0 = fmaxf(v0, 0.f); v1 = fmaxf(v1, 0.f);
    v2 = fmaxf(v2, 0.f); v3 = fmaxf(v3, 0.f);
  }
  st4(out + (size_t)n * EMBD + c, make_float4(v0, v1, v2, v3));
}

// ---------------------------------------------------------------------------
// Pool: batch sorted -> run-length accumulate, one atomic per (run, channel).
__global__ __launch_bounds__(256) void k_pool(const hfu* __restrict__ h,
                                              const int* __restrict__ batch,
                                              float* __restrict__ out) {
  const int c = threadIdx.x;
  const int n0 = blockIdx.x * 128;
  float acc = 0.f;
  int gprev = batch[n0];
  for (int i = 0; i < 128; ++i) {
    const int n = n0 + i;
    const int g = batch[n];
    if (g != gprev) {
      atomicAdd(&out[gprev * EMBD + c], acc);
      acc = 0.f;
      gprev = g;
    }
    acc += h2f(h[(size_t)n * EMBD + c]);
  }
  atomicAdd(&out[gprev * EMBD + c], acc);
}

// ---------------------------------------------------------------------------
extern "C" void kernel_launch(void* const* d_in, const int* in_sizes, int n_in,
                              void* d_out, int out_size, void* d_ws,
                              size_t ws_size, hipStream_t stream) {
  const float* atom_emb = (const float*)d_in[0];
  const float* bond_emb = (const float*)d_in[1];
  const float* W = (const float*)d_in[2];
  const float* b = (const float*)d_in[3];
  const float* root = (const float*)d_in[4];
  const float* gamma = (const float*)d_in[5];
  const float* beta = (const float*)d_in[6];
  const float* mean = (const float*)d_in[7];
  const float* var = (const float*)d_in[8];
  const int* x = (const int*)d_in[9];
  const int* ei = (const int*)d_in[10];
  const int* ea = (const int*)d_in[11];
  const int* batch = (const int*)d_in[12];
  float* out = (float*)d_out;

  const size_t H = (size_t)NN * EMBD;  // elements per h buffer
  // ws layout: X (fp16, 67MB) | Y (fp16, 67MB) | recs (NE int4, 4MB) |
  //            combo (3*60*256 f32, 184KB) | bnscale/bnshift (6KB)
  const size_t need = 2 * H * sizeof(hfu) + (size_t)NE * 16 +
                      (size_t)3 * 60 * EMBD * sizeof(float) +
                      2 * 3 * EMBD * sizeof(float);
  if (ws_size < need) {  // fails validation cleanly instead of faulting
    k_zero<<<1024, 256, 0, stream>>>((float4*)out, NG * EMBD / 4);
    return;
  }
  char* ws = (char*)d_ws;
  hfu* X = (hfu*)ws;
  hfu* Y = X + H;
  int4* recs = (int4*)(ws + 2 * H * sizeof(hfu));
  float* combo = (float*)(recs + NE);
  float* bnscale = combo + (size_t)3 * 60 * EMBD;
  float* bnshift = bnscale + 3 * EMBD;

  // graph metadata + fp16 Wt live in d_out (4 MiB) until the final pool
  float* deg = out;                        // NN f32
  float* dnv = out + NN;                   // NN f32
  int* bcnt = (int*)(out + 2 * NN);        // NN
  int* rowptr = bcnt + NN;                 // NN
  int* ticket = rowptr + NN;               // NN  (dead after k_scatter)
  int* bsum = ticket + NN;                 // 512
  hfu* Wt = (hfu*)ticket;                  // 3*64K fp16 = 384 KB <= 512 KB

  k_zero<<<1024, 256, 0, stream>>>((float4*)out, (5 * NN + 512) / 4);
  k_atom_encode<<<NN / 4, 256, 0, stream>>>(atom_emb, x, X);
  k_count<<<NE / 256, 256, 0, stream>>>(ei, deg, bcnt);
  k_bsum<<<NN / 256, 256, 0, stream>>>(bcnt, bsum);
  k_bscan<<<1, 512, 0, stream>>>(bsum);
  k_rowptr<<<NN / 256, 256, 0, stream>>>(bcnt, bsum, rowptr);
  k_finish_deg<<<NN / 256, 256, 0, stream>>>(deg, dnv);   // before scatter
  k_scatter<<<NE / 256, 256, 0, stream>>>(ei, ea, dnv, rowptr, ticket, recs);
  k_wt<<<3 * 256 * 256 / 256, 256, 0, stream>>>(W, Wt);   // ticket dead now
  k_combo<<<(3 * 60 * 64 + 255) / 256, 256, 0, stream>>>(bond_emb, combo);
  k_bnparam<<<3, 256, 0, stream>>>(gamma, beta, mean, var, bnscale, bnshift);

  for (int l = 0; l < 3; ++l) {
    k_gemm_mfma<<<NN / 64, 256, 0, stream>>>(
        X, Wt + l * 65536, b + l * EMBD, Y);
    k_gather_update<<<NN / 4, 256, 0, stream>>>(
        recs, combo + (size_t)l * 60 * EMBD, Y, dnv, bcnt, rowptr,
        root + l * EMBD, bnscale + l * EMBD, bnshift + l * EMBD, X,
        (l < 2) ? 1 : 0);
  }
  // metadata now dead: zero the full output, then pool h3 (in X) into it
  k_zero<<<1024, 256, 0, stream>>>((float4*)out, NG * EMBD / 4);
  k_pool<<<NN / 128, 256, 0, stream>>>(X, batch, out);
}